// Round 22
// baseline (73.980 us; speedup 1.0000x reference)
//
#include <hip/hip_runtime.h>
#include <hip/hip_bf16.h>
#include <stdint.h>

typedef __bf16 bf16_t;
typedef bf16_t bf16x8 __attribute__((ext_vector_type(8)));
typedef float f32x4 __attribute__((ext_vector_type(4)));

#define DEVI static __device__ __forceinline__

constexpr int NB = 32, CIN = 256, COUT = 256, KNUM = 6, ET = 3, TDIM = 64, VV = 25;
constexpr int KD   = KNUM * CIN;       // 1536 contraction dim (k,ci)
constexpr long OUT0 = (long)NB * COUT * TDIM * VV;  // 13107200 (x_sum elems)
constexpr int ACNT = ET * VV * VV;     // 1875 (A copy)

// wp3: W in fragment-order. 24 steps x 2048 chunks x 16B = 768 KB. (R7 layout)
constexpr int NSTEP = 24;              // 4 cb x 6 k
constexpr int WP3_CHUNKS = NSTEP * 2048;
constexpr size_t WP3_BYTES  = (size_t)WP3_CHUNKS * 16;      // 768 KB
constexpr size_t BIAS_OFF   = WP3_BYTES;
constexpr size_t BIAS_BYTES = (size_t)NB * VV * COUT * 4;   // bias [n][w][c] f32
constexpr size_t WS_NEED    = BIAS_OFF + BIAS_BYTES;

DEVI unsigned packbf(float lo, float hi) {
  unsigned short a = __builtin_bit_cast(unsigned short, (bf16_t)lo);
  unsigned short b = __builtin_bit_cast(unsigned short, (bf16_t)hi);
  return ((unsigned)b << 16) | (unsigned)a;
}

// ---------------- prep: wp3 fragment-layout + bias table + A copy ----------
__global__ __launch_bounds__(256) void prep_kernel(
    const float* __restrict__ A, const float* __restrict__ Bm,
    const float* __restrict__ lam_p, const float* __restrict__ W,
    const float* __restrict__ bvec, bf16_t* __restrict__ wp3,
    float* __restrict__ biasmat, float* __restrict__ outA)
{
  int idx = blockIdx.x * 256 + threadIdx.x;
  constexpr int S1 = WP3_CHUNKS;            // 49152 (one 16B chunk per thread)
  constexpr int S2 = S1 + NB * VV * COUT;   // +204800
  constexpr int S3 = S2 + ACNT;
  if (idx < S1) {
    int s  = idx >> 11;
    int r  = idx & 2047;
    int mi = r >> 7;
    int kk = (r >> 6) & 1;
    int ln = r & 63;
    int lg = ln >> 4, lw = ln & 15;
    int cb = s / 6, k = s - cb * 6;
    int cibase = cb * 64 + (lg + 4 * kk) * 8;
    int col = (k << 8) + mi * 16 + lw;
    bf16_t* dst = wp3 + ((long)idx << 3);
    #pragma unroll
    for (int e = 0; e < 8; ++e)
      dst[e] = (bf16_t)W[(cibase + e) * KD + col];
  } else if (idx < S2) {
    // bias[n][w][c] = sum_k b[k*256+c] * S[n,k,w],  S = col-sum of M (lam folded)
    int j = idx - S1;
    int c = j & 255;
    int nw = j >> 8;
    int w = nw % VV;
    int n = nw / VV;
    float lam = lam_p[0];
    float s = 0.f;
    for (int k = 0; k < KNUM; ++k) {
      float sk = 0.f;
      if (k < ET) {
        for (int v = 0; v < VV; ++v) sk += A[(k * VV + v) * VV + w];
      } else {
        for (int v = 0; v < VV; ++v) sk += Bm[(((n * ET) + (k - ET)) * VV + v) * VV + w];
        sk *= lam;
      }
      s += bvec[(k << 8) + c] * sk;
    }
    biasmat[j] = s;
  } else if (idx < S3) {
    int j = idx - S2;
    outA[j] = A[j];   // second tuple output: A passthrough
  }
}

// ---------------- fused kernel (R21 + 2-k intervals, quad-buffer Bs) ---------
// Per interval (3 per cb): #1 for k0,k1 -> Bs tiles [par*2+kh] (af2a(k0)
// prefetched under 8 MFMAs); ONE barrier; #2 for k0 then k1 (proven
// 4-load/16-MFMA batches). 12 barriers/block (was 24). Quad-buffer makes the
// end-of-interval barrier unnecessary (same proof as R17's dbuf invariant).
// LDS = Bs 64K + Ms 15K = 80,896 B -> exactly 2 blocks/CU.
__global__ __launch_bounds__(512, 4) void fused_kernel(
    const float* __restrict__ x, const float* __restrict__ A,
    const float* __restrict__ Bm, const float* __restrict__ lam_p,
    const bf16_t* __restrict__ wp3, const float* __restrict__ biasmat,
    float* __restrict__ out)
{
  __shared__ __align__(16) bf16_t Bs[4 * 128 * 64];  // 64 KB quad (epilogue: eb)
  __shared__ __align__(16) bf16_t Ms[KNUM * 32 * 40];// 15 KB, 80B rows

  const int b = blockIdx.x;
  const int n = b >> 4;                  // 0..31
  const int t0 = (b & 15) << 2;          // t-group of 4
  const int tid = threadIdx.x;
  const int wv = tid >> 6, ln = tid & 63;
  const int lw = ln & 15, lg = ln >> 4;
  const float lam = lam_p[0];

  // stage Ms once: row R=k*32+w (80B), group-XOR sw2=(w&3)^((w>>2)&3)
  for (int i = tid; i < KNUM * 32 * 32; i += 512) {
    int R = i >> 5, v = i & 31;
    int k = i >> 10, w = (i >> 5) & 31;
    float val = 0.f;
    if (w < VV && v < VV)
      val = (k < ET) ? A[(k * VV + v) * VV + w]
                     : lam * Bm[(((n * ET) + (k - ET)) * VV + v) * VV + w];
    int sw2 = (w & 3) ^ ((w >> 2) & 3);
    int byteoff = R * 80 + ((((v >> 3) ^ sw2) & 3) << 4) + ((v & 7) << 1);
    *(bf16_t*)((char*)Ms + byteoff) = (bf16_t)val;
  }
  __syncthreads();   // Ms visible (once)

  f32x4 acc[4][4] = {};
  const int m_base = (wv >> 1) * 64;
  const int mb4 = (wv >> 1) * 4;         // mi base for A-fragments
  const int n_base = (wv & 1) * 64;
  const int dtw = wv >> 1;               // this wave's dt for #1 rows
  const f32x4 z4 = {0.f, 0.f, 0.f, 0.f};
  const int msw2 = (lw & 3) ^ ((lw >> 2) & 3);   // Ms read swizzle

  #pragma unroll 1
  for (int cb = 0; cb < 4; ++cb) {
    // afx: this wave's x fragments for the whole cb, direct global->VGPR.
    bf16x8 afx[2];
    #pragma unroll
    for (int rt = 0; rt < 2; ++rt) {
      int ci = (wv & 1) * 32 + rt * 16 + lw;
      const float* xp = x + ((long)(n * CIN + cb * 64 + ci) * TDIM + t0 + dtw) * VV;
      float xv[8];
      if (lg < 3) {
        #pragma unroll
        for (int e = 0; e < 8; ++e) xv[e] = xp[lg * 8 + e];
      } else {
        xv[0] = xp[24];
        #pragma unroll
        for (int e = 1; e < 8; ++e) xv[e] = 0.f;
      }
      union { unsigned u[4]; bf16x8 v; } u;
      u.u[0] = packbf(xv[0], xv[1]); u.u[1] = packbf(xv[2], xv[3]);
      u.u[2] = packbf(xv[4], xv[5]); u.u[3] = packbf(xv[6], xv[7]);
      afx[rt] = u.v;
    }

    #pragma unroll 1
    for (int ki = 0; ki < 3; ++ki) {     // interval = 2 k-steps
      const int ii = cb * 3 + ki;
      const int s0 = cb * 6 + ki * 2;
      const int base = (ii & 1) * 2 * 8192;   // this interval's two tiles
      const bf16_t* wpS0 = wp3 + (((long)s0 * 2048 + (long)mb4 * 128 + ln) << 3);
      const bf16_t* wpS1 = wp3 + (((long)(s0 + 1) * 2048 + (long)mb4 * 128 + ln) << 3);

      // af2a(k0): issued early, completes under the interval's 8 #1-MFMAs
      bf16x8 af2a[4];
      #pragma unroll
      for (int i = 0; i < 4; ++i)
        af2a[i] = *(const bf16x8*)(wpS0 + ((i * 128) << 3));

      // ---- #1 for both k's -> Bs tiles [base + kh*8192] ----
      #pragma unroll
      for (int kh = 0; kh < 2; ++kh) {
        const int kq = ki * 2 + kh;
        const int bufk = base + kh * 8192;
        bf16x8 mb0 = *(const bf16x8*)((const char*)Ms + (kq * 32 + lw) * 80 + (((lg ^ msw2) & 3) << 4));
        bf16x8 mb1 = *(const bf16x8*)((const char*)Ms + (kq * 32 + 16 + lw) * 80 + (((lg ^ msw2) & 3) << 4));
        #pragma unroll
        for (int rt = 0; rt < 2; ++rt) {
          f32x4 d0 = __builtin_amdgcn_mfma_f32_16x16x32_bf16(afx[rt], mb0, z4, 0, 0, 0);
          f32x4 d1 = __builtin_amdgcn_mfma_f32_16x16x32_bf16(afx[rt], mb1, z4, 0, 0, 0);
          int rbase = wv * 32 + rt * 16 + (lg << 2);
          int dt = rbase >> 6, ci0 = rbase & 63;
          int r0 = dt * 32 + lw;
          int g0 = ((ci0 >> 3) ^ (r0 & 7)) & 7;
          uint2 p0; p0.x = packbf(d0[0], d0[1]); p0.y = packbf(d0[2], d0[3]);
          *(uint2*)((char*)(Bs + bufk) + r0 * 128 + (g0 << 4) + ((ci0 << 1) & 15)) = p0;
          uint2 p1; p1.x = packbf(d1[0], d1[1]); p1.y = packbf(d1[2], d1[3]);
          *(uint2*)((char*)(Bs + bufk) + (r0 + 16) * 128 + (g0 << 4) + ((ci0 << 1) & 15)) = p1;
        }
      }
      __syncthreads();   // both tiles ready (the ONLY barrier per interval)

      __builtin_amdgcn_s_setprio(1);
      // ---- #2 for k0 ----
      {
        const int bufk = base;
        bf16x8 bf2[4];
        #pragma unroll
        for (int j = 0; j < 4; ++j) {
          int rr = n_base + j * 16 + lw;
          int gg = (lg ^ (rr & 7)) & 7;
          bf2[j] = *(const bf16x8*)((const char*)(Bs + bufk) + rr * 128 + (gg << 4));
        }
        #pragma unroll
        for (int i = 0; i < 4; ++i)
          #pragma unroll
          for (int j = 0; j < 4; ++j)
            acc[i][j] = __builtin_amdgcn_mfma_f32_16x16x32_bf16(af2a[i], bf2[j], acc[i][j], 0, 0, 0);
        bf16x8 af2b[4];
        #pragma unroll
        for (int i = 0; i < 4; ++i)
          af2b[i] = *(const bf16x8*)(wpS0 + ((i * 128 + 64) << 3));
        #pragma unroll
        for (int j = 0; j < 4; ++j) {
          int rr = n_base + j * 16 + lw;
          int gg = ((4 + lg) ^ (rr & 7)) & 7;
          bf2[j] = *(const bf16x8*)((const char*)(Bs + bufk) + rr * 128 + (gg << 4));
        }
        #pragma unroll
        for (int i = 0; i < 4; ++i)
          #pragma unroll
          for (int j = 0; j < 4; ++j)
            acc[i][j] = __builtin_amdgcn_mfma_f32_16x16x32_bf16(af2b[i], bf2[j], acc[i][j], 0, 0, 0);
      }
      // ---- #2 for k1 ----
      {
        const int bufk = base + 8192;
        bf16x8 af2c[4];
        #pragma unroll
        for (int i = 0; i < 4; ++i)
          af2c[i] = *(const bf16x8*)(wpS1 + ((i * 128) << 3));
        bf16x8 bf2[4];
        #pragma unroll
        for (int j = 0; j < 4; ++j) {
          int rr = n_base + j * 16 + lw;
          int gg = (lg ^ (rr & 7)) & 7;
          bf2[j] = *(const bf16x8*)((const char*)(Bs + bufk) + rr * 128 + (gg << 4));
        }
        #pragma unroll
        for (int i = 0; i < 4; ++i)
          #pragma unroll
          for (int j = 0; j < 4; ++j)
            acc[i][j] = __builtin_amdgcn_mfma_f32_16x16x32_bf16(af2c[i], bf2[j], acc[i][j], 0, 0, 0);
        bf16x8 af2d[4];
        #pragma unroll
        for (int i = 0; i < 4; ++i)
          af2d[i] = *(const bf16x8*)(wpS1 + ((i * 128 + 64) << 3));
        #pragma unroll
        for (int j = 0; j < 4; ++j) {
          int rr = n_base + j * 16 + lw;
          int gg = ((4 + lg) ^ (rr & 7)) & 7;
          bf2[j] = *(const bf16x8*)((const char*)(Bs + bufk) + rr * 128 + (gg << 4));
        }
        #pragma unroll
        for (int i = 0; i < 4; ++i)
          #pragma unroll
          for (int j = 0; j < 4; ++j)
            acc[i][j] = __builtin_amdgcn_mfma_f32_16x16x32_bf16(af2d[i], bf2[j], acc[i][j], 0, 0, 0);
      }
      __builtin_amdgcn_s_setprio(0);
      // (no end-of-interval barrier: quad-buffer invariant proves safety)
    }
  }

  // ---- epilogue: LDS-bounce dense writes (bias folded at eb-write) ----------
  __syncthreads();   // all #2 reads of Bs complete
  float* eb = (float*)Bs;   // 64 x 100 f32 = 25.6 KB
  #pragma unroll 1
  for (int rnd = 0; rnd < 4; ++rnd) {
    if ((wv >> 1) == rnd) {
      #pragma unroll
      for (int j = 0; j < 4; ++j) {
        int col = n_base + j * 16 + lw;
        int dt = col >> 5, w = col & 31;
        if (w < VV) {
          const float* brow = biasmat + (n * 25 + w) * 256 + rnd * 64;
          #pragma unroll
          for (int i = 0; i < 4; ++i) {
            #pragma unroll
            for (int r = 0; r < 4; ++r) {
              int cl = i * 16 + (lg << 2) + r;
              eb[cl * 100 + dt * 25 + w] = acc[i][j][r] + brow[cl];
            }
          }
        }
      }
    }
    __syncthreads();
    #pragma unroll
    for (int it = 0; it < 4; ++it) {
      int idx = it * 512 + tid;
      if (idx < 1600) {
        int cl = idx / 25, f4 = idx - cl * 25;
        f32x4 val = *(const f32x4*)(eb + cl * 100 + f4 * 4);
        *(f32x4*)(out + (long)n * 409600 + (long)(rnd * 64 + cl) * 1600
                      + t0 * 25 + f4 * 4) = val;
      }
    }
    __syncthreads();   // eb free for next round
  }
}

// ---------------- ws-free fp32 fallback (insurance) ----------------
__global__ __launch_bounds__(256) void fallback_kernel(
    const float* __restrict__ x, const float* __restrict__ A,
    const float* __restrict__ Bm, const float* __restrict__ lam_p,
    const float* __restrict__ W, const float* __restrict__ bvec,
    float* __restrict__ out)
{
  __shared__ __align__(16) float xs[CIN][28];
  __shared__ __align__(16) float Ms[KNUM][VV][28];   // [k][v][w] padded
  const int nt = blockIdx.x;
  const int n = nt >> 6, t = nt & 63;
  const int tid = threadIdx.x;
  const float lam = lam_p[0];

  const float* xp = x + (((long)(n * CIN + tid) * TDIM + t) * VV);
  #pragma unroll
  for (int v = 0; v < VV; ++v) xs[tid][v] = xp[v];
  xs[tid][25] = xs[tid][26] = xs[tid][27] = 0.f;
  for (int i = tid; i < KNUM * VV * VV; i += 256) {
    int k = i / (VV * VV);
    int r = i - k * VV * VV;
    int v = r / VV;
    int w = r - v * VV;
    Ms[k][v][w] = (k < ET) ? A[(k * VV + v) * VV + w]
                           : lam * Bm[(((n * ET) + (k - ET)) * VV + v) * VV + w];
    if (w == 24) { Ms[k][v][25] = Ms[k][v][26] = Ms[k][v][27] = 0.f; }
  }
  __syncthreads();

  float oacc[28] = {};
  for (int k = 0; k < KNUM; ++k) {
    float yv[28];
    float bv = bvec[(k << 8) + tid];
    #pragma unroll
    for (int v = 0; v < 28; ++v) yv[v] = 0.f;
    for (int ci = 0; ci < CIN; ++ci) {
      float wl = W[ci * KD + (k << 8) + tid];
      const f32x4* x4 = (const f32x4*)&xs[ci][0];
      #pragma unroll
      for (int q = 0; q < 7; ++q) {
        f32x4 xv = x4[q];
        yv[q*4+0] += wl*xv[0]; yv[q*4+1] += wl*xv[1];
        yv[q*4+2] += wl*xv[2]; yv[q*4+3] += wl*xv[3];
      }
    }
    #pragma unroll
    for (int v = 0; v < VV; ++v) {
      float yvv = yv[v] + bv;
      const f32x4* m4 = (const f32x4*)&Ms[k][v][0];
      #pragma unroll
      for (int q = 0; q < 7; ++q) {
        f32x4 mv = m4[q];
        oacc[q*4+0] += yvv*mv[0]; oacc[q*4+1] += yvv*mv[1];
        oacc[q*4+2] += yvv*mv[2]; oacc[q*4+3] += yvv*mv[3];
      }
    }
  }
  float* op = out + (((long)(n * COUT + tid) * TDIM + t) * VV);
  #pragma unroll
  for (int w = 0; w < VV; ++w) op[w] = oacc[w];
}

__global__ void copyA_kernel(const float* __restrict__ A, float* __restrict__ outA) {
  int i = blockIdx.x * 256 + threadIdx.x;
  if (i < ACNT) outA[i] = A[i];
}

extern "C" void kernel_launch(void* const* d_in, const int* in_sizes, int n_in,
                              void* d_out, int out_size, void* d_ws, size_t ws_size,
                              hipStream_t stream) {
  const float* x   = (const float*)d_in[0];
  const float* A   = (const float*)d_in[1];
  const float* Bm  = (const float*)d_in[2];
  const float* lam = (const float*)d_in[3];
  const float* W   = (const float*)d_in[4];
  const float* bv  = (const float*)d_in[5];
  float* out = (float*)d_out;

  if (d_ws != nullptr && ws_size >= WS_NEED) {
    bf16_t* wp3     = (bf16_t*)d_ws;
    float*  biasmat = (float*)((char*)d_ws + BIAS_OFF);
    constexpr int PREP_ITEMS = WP3_CHUNKS + NB * VV * COUT + ACNT;
    prep_kernel<<<(PREP_ITEMS + 255) / 256, 256, 0, stream>>>(A, Bm, lam, W, bv, wp3, biasmat, out + OUT0);
    fused_kernel<<<NB * 16, 512, 0, stream>>>(x, A, Bm, lam, wp3, biasmat, out);
  } else {
    fallback_kernel<<<NB * TDIM, 256, 0, stream>>>(x, A, Bm, lam, W, bv, out);
    copyA_kernel<<<(ACNT + 255) / 256, 256, 0, stream>>>(A, out + OUT0);
  }
}

// Round 23
// 73.416 us; speedup vs baseline: 1.0077x; 1.0077x over previous
//
#include <hip/hip_runtime.h>
#include <hip/hip_bf16.h>
#include <stdint.h>

typedef __bf16 bf16_t;
typedef bf16_t bf16x8 __attribute__((ext_vector_type(8)));
typedef float f32x4 __attribute__((ext_vector_type(4)));

#define DEVI static __device__ __forceinline__

constexpr int NB = 32, CIN = 256, COUT = 256, KNUM = 6, ET = 3, TDIM = 64, VV = 25;
constexpr int KD   = KNUM * CIN;       // 1536 contraction dim (k,ci)
constexpr long OUT0 = (long)NB * COUT * TDIM * VV;  // 13107200 (x_sum elems)
constexpr int ACNT = ET * VV * VV;     // 1875 (A copy)

// wp3: W in fragment-order. 24 steps x 2048 chunks x 16B = 768 KB. (R7 layout)
constexpr int NSTEP = 24;              // 4 cb x 6 k
constexpr int WP3_CHUNKS = NSTEP * 2048;
constexpr size_t WP3_BYTES  = (size_t)WP3_CHUNKS * 16;      // 768 KB
constexpr size_t BIAS_OFF   = WP3_BYTES;
constexpr size_t BIAS_BYTES = (size_t)NB * VV * COUT * 4;   // bias [n][w][c] f32
constexpr size_t WS_NEED    = BIAS_OFF + BIAS_BYTES;

DEVI unsigned packbf(float lo, float hi) {
  unsigned short a = __builtin_bit_cast(unsigned short, (bf16_t)lo);
  unsigned short b = __builtin_bit_cast(unsigned short, (bf16_t)hi);
  return ((unsigned)b << 16) | (unsigned)a;
}

// ---------------- prep: wp3 fragment-layout + bias table + A copy ----------
__global__ __launch_bounds__(256) void prep_kernel(
    const float* __restrict__ A, const float* __restrict__ Bm,
    const float* __restrict__ lam_p, const float* __restrict__ W,
    const float* __restrict__ bvec, bf16_t* __restrict__ wp3,
    float* __restrict__ biasmat, float* __restrict__ outA)
{
  int idx = blockIdx.x * 256 + threadIdx.x;
  constexpr int S1 = WP3_CHUNKS;            // 49152 (one 16B chunk per thread)
  constexpr int S2 = S1 + NB * VV * COUT;   // +204800
  constexpr int S3 = S2 + ACNT;
  if (idx < S1) {
    int s  = idx >> 11;
    int r  = idx & 2047;
    int mi = r >> 7;
    int kk = (r >> 6) & 1;
    int ln = r & 63;
    int lg = ln >> 4, lw = ln & 15;
    int cb = s / 6, k = s - cb * 6;
    int cibase = cb * 64 + (lg + 4 * kk) * 8;
    int col = (k << 8) + mi * 16 + lw;
    bf16_t* dst = wp3 + ((long)idx << 3);
    #pragma unroll
    for (int e = 0; e < 8; ++e)
      dst[e] = (bf16_t)W[(cibase + e) * KD + col];
  } else if (idx < S2) {
    // bias[n][w][c] = sum_k b[k*256+c] * S[n,k,w],  S = col-sum of M (lam folded)
    int j = idx - S1;
    int c = j & 255;
    int nw = j >> 8;
    int w = nw % VV;
    int n = nw / VV;
    float lam = lam_p[0];
    float s = 0.f;
    for (int k = 0; k < KNUM; ++k) {
      float sk = 0.f;
      if (k < ET) {
        for (int v = 0; v < VV; ++v) sk += A[(k * VV + v) * VV + w];
      } else {
        for (int v = 0; v < VV; ++v) sk += Bm[(((n * ET) + (k - ET)) * VV + v) * VV + w];
        sk *= lam;
      }
      s += bvec[(k << 8) + c] * sk;
    }
    biasmat[j] = s;
  } else if (idx < S3) {
    int j = idx - S2;
    outA[j] = A[j];   // second tuple output: A passthrough
  }
}

// ---------------- fused kernel (R21: best measured, 73.6 us) -----------------
// Per cb, per wave: afx loaded once global->VGPR. Per step: af2a <- wp3
// (completes under #1, T14); MFMA#1 afx x Ms -> Bs[buf] (dbuf, uint2 writes);
// ONE barrier; MFMA#2 kk=0 (prefetched) / kk=1 (at use). No end-of-step
// barrier (dbuf invariant). LDS 47 KB; regs 64V+64A = 128 (4 waves/SIMD tier).
__global__ __launch_bounds__(512, 4) void fused_kernel(
    const float* __restrict__ x, const float* __restrict__ A,
    const float* __restrict__ Bm, const float* __restrict__ lam_p,
    const bf16_t* __restrict__ wp3, const float* __restrict__ biasmat,
    float* __restrict__ out)
{
  __shared__ __align__(16) bf16_t Bs[2 * 128 * 64];  // 32 KB dbuf (epilogue: eb)
  __shared__ __align__(16) bf16_t Ms[KNUM * 32 * 40];// 15 KB, 80B rows

  const int b = blockIdx.x;
  const int n = b >> 4;                  // 0..31
  const int t0 = (b & 15) << 2;          // t-group of 4
  const int tid = threadIdx.x;
  const int wv = tid >> 6, ln = tid & 63;
  const int lw = ln & 15, lg = ln >> 4;
  const float lam = lam_p[0];

  // stage Ms once: row R=k*32+w (80B), group-XOR sw2=(w&3)^((w>>2)&3)
  for (int i = tid; i < KNUM * 32 * 32; i += 512) {
    int R = i >> 5, v = i & 31;
    int k = i >> 10, w = (i >> 5) & 31;
    float val = 0.f;
    if (w < VV && v < VV)
      val = (k < ET) ? A[(k * VV + v) * VV + w]
                     : lam * Bm[(((n * ET) + (k - ET)) * VV + v) * VV + w];
    int sw2 = (w & 3) ^ ((w >> 2) & 3);
    int byteoff = R * 80 + ((((v >> 3) ^ sw2) & 3) << 4) + ((v & 7) << 1);
    *(bf16_t*)((char*)Ms + byteoff) = (bf16_t)val;
  }
  __syncthreads();   // Ms visible (once)

  f32x4 acc[4][4] = {};
  const int m_base = (wv >> 1) * 64;
  const int mb4 = (wv >> 1) * 4;         // mi base for A-fragments
  const int n_base = (wv & 1) * 64;
  const int dtw = wv >> 1;               // this wave's dt for #1 rows
  const f32x4 z4 = {0.f, 0.f, 0.f, 0.f};
  const int msw2 = (lw & 3) ^ ((lw >> 2) & 3);   // Ms read swizzle

  #pragma unroll 1
  for (int cb = 0; cb < 4; ++cb) {
    // afx: this wave's x fragments for the whole cb, direct global->VGPR.
    bf16x8 afx[2];
    #pragma unroll
    for (int rt = 0; rt < 2; ++rt) {
      int ci = (wv & 1) * 32 + rt * 16 + lw;
      const float* xp = x + ((long)(n * CIN + cb * 64 + ci) * TDIM + t0 + dtw) * VV;
      float xv[8];
      if (lg < 3) {
        #pragma unroll
        for (int e = 0; e < 8; ++e) xv[e] = xp[lg * 8 + e];
      } else {
        xv[0] = xp[24];
        #pragma unroll
        for (int e = 1; e < 8; ++e) xv[e] = 0.f;
      }
      union { unsigned u[4]; bf16x8 v; } u;
      u.u[0] = packbf(xv[0], xv[1]); u.u[1] = packbf(xv[2], xv[3]);
      u.u[2] = packbf(xv[4], xv[5]); u.u[3] = packbf(xv[6], xv[7]);
      afx[rt] = u.v;
    }

    #pragma unroll 1
    for (int k = 0; k < KNUM; ++k) {
      const int s = cb * 6 + k;
      const int buf = (s & 1) * (128 * 64);
      const bf16_t* wpS = wp3 + (((long)s * 2048 + (long)mb4 * 128 + ln) << 3);

      // A fragments kk=0: issued early, complete under #1 (T14 issue-early)
      bf16x8 af2a[4];
      #pragma unroll
      for (int i = 0; i < 4; ++i)
        af2a[i] = *(const bf16x8*)(wpS + ((i * 128) << 3));

      // MFMA#1: afx x Ms -> Bs[buf]  (uint2 b64 pack-writes, 8B-aligned)
      bf16x8 mb0 = *(const bf16x8*)((const char*)Ms + (k * 32 + lw) * 80 + (((lg ^ msw2) & 3) << 4));
      bf16x8 mb1 = *(const bf16x8*)((const char*)Ms + (k * 32 + 16 + lw) * 80 + (((lg ^ msw2) & 3) << 4));
      #pragma unroll
      for (int rt = 0; rt < 2; ++rt) {
        f32x4 d0 = __builtin_amdgcn_mfma_f32_16x16x32_bf16(afx[rt], mb0, z4, 0, 0, 0);
        f32x4 d1 = __builtin_amdgcn_mfma_f32_16x16x32_bf16(afx[rt], mb1, z4, 0, 0, 0);
        int rbase = wv * 32 + rt * 16 + (lg << 2);
        int dt = rbase >> 6, ci0 = rbase & 63;
        int r0 = dt * 32 + lw;
        int g0 = ((ci0 >> 3) ^ (r0 & 7)) & 7;
        uint2 p0; p0.x = packbf(d0[0], d0[1]); p0.y = packbf(d0[2], d0[3]);
        *(uint2*)((char*)(Bs + buf) + r0 * 128 + (g0 << 4) + ((ci0 << 1) & 15)) = p0;
        uint2 p1; p1.x = packbf(d1[0], d1[1]); p1.y = packbf(d1[2], d1[3]);
        *(uint2*)((char*)(Bs + buf) + (r0 + 16) * 128 + (g0 << 4) + ((ci0 << 1) & 15)) = p1;
      }
      __syncthreads();   // Bs[buf] ready (the ONLY barrier per step; dbuf covers rest)

      // MFMA#2 kk=0 (prefetched A-frags)
      __builtin_amdgcn_s_setprio(1);
      {
        bf16x8 bf2[4];
        #pragma unroll
        for (int j = 0; j < 4; ++j) {
          int rr = n_base + j * 16 + lw;
          int gg = (lg ^ (rr & 7)) & 7;
          bf2[j] = *(const bf16x8*)((const char*)(Bs + buf) + rr * 128 + (gg << 4));
        }
        #pragma unroll
        for (int i = 0; i < 4; ++i)
          #pragma unroll
          for (int j = 0; j < 4; ++j)
            acc[i][j] = __builtin_amdgcn_mfma_f32_16x16x32_bf16(af2a[i], bf2[j], acc[i][j], 0, 0, 0);
      }
      // MFMA#2 kk=1 (A-frags loaded at use; TLP covers the L2 latency)
      {
        bf16x8 af2b[4];
        #pragma unroll
        for (int i = 0; i < 4; ++i)
          af2b[i] = *(const bf16x8*)(wpS + ((i * 128 + 64) << 3));
        bf16x8 bf2[4];
        #pragma unroll
        for (int j = 0; j < 4; ++j) {
          int rr = n_base + j * 16 + lw;
          int gg = ((4 + lg) ^ (rr & 7)) & 7;
          bf2[j] = *(const bf16x8*)((const char*)(Bs + buf) + rr * 128 + (gg << 4));
        }
        #pragma unroll
        for (int i = 0; i < 4; ++i)
          #pragma unroll
          for (int j = 0; j < 4; ++j)
            acc[i][j] = __builtin_amdgcn_mfma_f32_16x16x32_bf16(af2b[i], bf2[j], acc[i][j], 0, 0, 0);
      }
      __builtin_amdgcn_s_setprio(0);
      // (no end-of-step barrier: dbuf invariant proves safety)
    }
  }

  // ---- epilogue: LDS-bounce dense writes (bias folded at eb-write) ----------
  __syncthreads();   // all #2 reads of Bs complete
  float* eb = (float*)Bs;   // 64 x 100 f32 = 25.6 KB
  #pragma unroll 1
  for (int rnd = 0; rnd < 4; ++rnd) {
    if ((wv >> 1) == rnd) {
      #pragma unroll
      for (int j = 0; j < 4; ++j) {
        int col = n_base + j * 16 + lw;
        int dt = col >> 5, w = col & 31;
        if (w < VV) {
          const float* brow = biasmat + (n * 25 + w) * 256 + rnd * 64;
          #pragma unroll
          for (int i = 0; i < 4; ++i) {
            #pragma unroll
            for (int r = 0; r < 4; ++r) {
              int cl = i * 16 + (lg << 2) + r;
              eb[cl * 100 + dt * 25 + w] = acc[i][j][r] + brow[cl];
            }
          }
        }
      }
    }
    __syncthreads();
    #pragma unroll
    for (int it = 0; it < 4; ++it) {
      int idx = it * 512 + tid;
      if (idx < 1600) {
        int cl = idx / 25, f4 = idx - cl * 25;
        f32x4 val = *(const f32x4*)(eb + cl * 100 + f4 * 4);
        *(f32x4*)(out + (long)n * 409600 + (long)(rnd * 64 + cl) * 1600
                      + t0 * 25 + f4 * 4) = val;
      }
    }
    __syncthreads();   // eb free for next round
  }
}

// ---------------- ws-free fp32 fallback (insurance) ----------------
__global__ __launch_bounds__(256) void fallback_kernel(
    const float* __restrict__ x, const float* __restrict__ A,
    const float* __restrict__ Bm, const float* __restrict__ lam_p,
    const float* __restrict__ W, const float* __restrict__ bvec,
    float* __restrict__ out)
{
  __shared__ __align__(16) float xs[CIN][28];
  __shared__ __align__(16) float Ms[KNUM][VV][28];   // [k][v][w] padded
  const int nt = blockIdx.x;
  const int n = nt >> 6, t = nt & 63;
  const int tid = threadIdx.x;
  const float lam = lam_p[0];

  const float* xp = x + (((long)(n * CIN + tid) * TDIM + t) * VV);
  #pragma unroll
  for (int v = 0; v < VV; ++v) xs[tid][v] = xp[v];
  xs[tid][25] = xs[tid][26] = xs[tid][27] = 0.f;
  for (int i = tid; i < KNUM * VV * VV; i += 256) {
    int k = i / (VV * VV);
    int r = i - k * VV * VV;
    int v = r / VV;
    int w = r - v * VV;
    Ms[k][v][w] = (k < ET) ? A[(k * VV + v) * VV + w]
                           : lam * Bm[(((n * ET) + (k - ET)) * VV + v) * VV + w];
    if (w == 24) { Ms[k][v][25] = Ms[k][v][26] = Ms[k][v][27] = 0.f; }
  }
  __syncthreads();

  float oacc[28] = {};
  for (int k = 0; k < KNUM; ++k) {
    float yv[28];
    float bv = bvec[(k << 8) + tid];
    #pragma unroll
    for (int v = 0; v < 28; ++v) yv[v] = 0.f;
    for (int ci = 0; ci < CIN; ++ci) {
      float wl = W[ci * KD + (k << 8) + tid];
      const f32x4* x4 = (const f32x4*)&xs[ci][0];
      #pragma unroll
      for (int q = 0; q < 7; ++q) {
        f32x4 xv = x4[q];
        yv[q*4+0] += wl*xv[0]; yv[q*4+1] += wl*xv[1];
        yv[q*4+2] += wl*xv[2]; yv[q*4+3] += wl*xv[3];
      }
    }
    #pragma unroll
    for (int v = 0; v < VV; ++v) {
      float yvv = yv[v] + bv;
      const f32x4* m4 = (const f32x4*)&Ms[k][v][0];
      #pragma unroll
      for (int q = 0; q < 7; ++q) {
        f32x4 mv = m4[q];
        oacc[q*4+0] += yvv*mv[0]; oacc[q*4+1] += yvv*mv[1];
        oacc[q*4+2] += yvv*mv[2]; oacc[q*4+3] += yvv*mv[3];
      }
    }
  }
  float* op = out + (((long)(n * COUT + tid) * TDIM + t) * VV);
  #pragma unroll
  for (int w = 0; w < VV; ++w) op[w] = oacc[w];
}

__global__ void copyA_kernel(const float* __restrict__ A, float* __restrict__ outA) {
  int i = blockIdx.x * 256 + threadIdx.x;
  if (i < ACNT) outA[i] = A[i];
}

extern "C" void kernel_launch(void* const* d_in, const int* in_sizes, int n_in,
                              void* d_out, int out_size, void* d_ws, size_t ws_size,
                              hipStream_t stream) {
  const float* x   = (const float*)d_in[0];
  const float* A   = (const float*)d_in[1];
  const float* Bm  = (const float*)d_in[2];
  const float* lam = (const float*)d_in[3];
  const float* W   = (const float*)d_in[4];
  const float* bv  = (const float*)d_in[5];
  float* out = (float*)d_out;

  if (d_ws != nullptr && ws_size >= WS_NEED) {
    bf16_t* wp3     = (bf16_t*)d_ws;
    float*  biasmat = (float*)((char*)d_ws + BIAS_OFF);
    constexpr int PREP_ITEMS = WP3_CHUNKS + NB * VV * COUT + ACNT;
    prep_kernel<<<(PREP_ITEMS + 255) / 256, 256, 0, stream>>>(A, Bm, lam, W, bv, wp3, biasmat, out + OUT0);
    fused_kernel<<<NB * 16, 512, 0, stream>>>(x, A, Bm, lam, wp3, biasmat, out);
  } else {
    fallback_kernel<<<NB * TDIM, 256, 0, stream>>>(x, A, Bm, lam, W, bv, out);
    copyA_kernel<<<(ACNT + 255) / 256, 256, 0, stream>>>(A, out + OUT0);
  }
}